// Round 12
// baseline (106.227 us; speedup 1.0000x reference)
//
#include <hip/hip_runtime.h>
#include <hip/hip_bf16.h>
#include <math.h>

#define SEQ 2048
#define HDIM 768
#define NH 12
#define HD 64
#define LR 384
#define EOT 50256

typedef short s16x8 __attribute__((ext_vector_type(8)));
typedef float f32x4 __attribute__((ext_vector_type(4)));
typedef unsigned short u16x8 __attribute__((ext_vector_type(8)));
typedef unsigned short u16x4 __attribute__((ext_vector_type(4)));

__device__ __forceinline__ unsigned short f2bf(float f) {
    union { float f; unsigned u; } v; v.f = f;
    unsigned r = v.u + 0x7fffu + ((v.u >> 16) & 1u);
    return (unsigned short)(r >> 16);
}

// async 16B global->LDS (linear dest; caller pre-swizzles the SOURCE chunk)
__device__ __forceinline__ void gl_lds16(const void* g, void* l) {
    __builtin_amdgcn_global_load_lds(
        (const __attribute__((address_space(1))) unsigned int*)g,
        (__attribute__((address_space(3))) unsigned int*)l, 16, 0, 0);
}

// ---------------- weight transpose+pack + x pack + bias concat + EOT scan ----------------
__global__ __launch_bounds__(256)
void transpose_pack_all(const float* w0, const float* w1, const float* w2, const float* w3,
                        const float* w4, const float* w5, const float* w6, const float* w7,
                        unsigned short* t0, unsigned short* t1, unsigned short* t2, unsigned short* t3,
                        unsigned short* t4, unsigned short* t5, unsigned short* t6, unsigned short* t7,
                        const float* x, unsigned short* xb,
                        const float* qd_b, const float* kvd_b, const float* qr_b, const float* kr_b,
                        const float* qu_b, const float* ku_b, const float* vu_b,
                        float* biasA, float* biasB,
                        const int* tok, int* lastEOT) {
    __shared__ float t[64][65];
    __shared__ int smax[256];
    int b = blockIdx.x;
    const int tid = threadIdx.x;
    if (b == 1129) {  // parallel lastEOT scan
        const int base = tid * 8;
        int v[8];
        int mx = 0;
#pragma unroll
        for (int j = 0; j < 8; ++j) {
            int i = base + j;
            int f = (tok[i] == EOT) ? i : 0;
            mx = max(mx, f);
            v[j] = mx;
        }
        smax[tid] = mx;
        __syncthreads();
        for (int off = 1; off < 256; off <<= 1) {
            int val = (tid >= off) ? smax[tid - off] : 0;
            __syncthreads();
            smax[tid] = max(smax[tid], val);
            __syncthreads();
        }
        int pre = (tid > 0) ? smax[tid - 1] : 0;
#pragma unroll
        for (int j = 0; j < 8; ++j) lastEOT[base + j] = max(pre, v[j]);
        return;
    }
    if (b == 1128) {  // bias concat
        for (int i = tid; i < 896; i += 256) {
            float v;
            if (i < 384) v = qd_b[i];
            else if (i < 768) v = kvd_b[i - 384];
            else if (i < 832) v = qr_b[i - 768];
            else v = kr_b[i - 832];
            biasA[i] = v;
        }
        for (int i = tid; i < 3072; i += 256) {
            float v;
            if (i < 768) v = qu_b[i];
            else if (i < 1536) v = ku_b[i - 768];
            else v = vu_b[i - 1536];
            biasB[i] = v;
        }
        return;
    }
    if (b >= 744) {  // x pack: 384 tiles of 64x64 (float4 in, u16x4 out)
        int b2 = b - 744;
        int row0 = (b2 / 12) * 64, col0 = (b2 % 12) * 64;
#pragma unroll
        for (int i = 0; i < 4; ++i) {
            int idx = tid + i * 256;
            int r = idx >> 4, c4 = (idx & 15) * 4;
            float4 v = *(const float4*)(x + (size_t)(row0 + r) * HDIM + col0 + c4);
            u16x4 pk = {f2bf(v.x), f2bf(v.y), f2bf(v.z), f2bf(v.w)};
            *(u16x4*)(xb + (size_t)(row0 + r) * HDIM + col0 + c4) = pk;
        }
        return;
    }
    const float* W; unsigned short* T; int K, N, lt;
    if      (b < 72)  { W = w0; T = t0; K = 768;  N = 384;  lt = b; }
    else if (b < 144) { W = w1; T = t1; K = 384;  N = 768;  lt = b - 72; }
    else if (b < 156) { W = w2; T = t2; K = 768;  N = 64;   lt = b - 144; }
    else if (b < 228) { W = w3; T = t3; K = 768;  N = 384;  lt = b - 156; }
    else if (b < 300) { W = w4; T = t4; K = 384;  N = 768;  lt = b - 228; }
    else if (b < 444) { W = w5; T = t5; K = 384;  N = 1536; lt = b - 300; }
    else if (b < 456) { W = w6; T = t6; K = 768;  N = 64;   lt = b - 444; }
    else              { W = w7; T = t7; K = 1536; N = 768;  lt = b - 456; }
    const int tn = N >> 6;
    const int n0 = (lt % tn) * 64, k0 = (lt / tn) * 64;
#pragma unroll
    for (int i = 0; i < 4; ++i) {
        int idx = tid + i * 256;
        int k = idx >> 4, c4 = (idx & 15) * 4;
        float4 v = *(const float4*)(W + (size_t)(k0 + k) * N + n0 + c4);
        t[k][c4] = v.x; t[k][c4 + 1] = v.y; t[k][c4 + 2] = v.z; t[k][c4 + 3] = v.w;
    }
    __syncthreads();
#pragma unroll
    for (int i = 0; i < 4; ++i) {
        int idx = tid + i * 256;
        int n = idx >> 4, k4 = (idx & 15) * 4;
        u16x4 pk = {f2bf(t[k4][n]), f2bf(t[k4 + 1][n]), f2bf(t[k4 + 2][n]), f2bf(t[k4 + 3][n])};
        *(u16x4*)(T + (size_t)(n0 + n) * K + k0 + k4) = pk;
    }
}

// ---------------- bf16 MFMA GEMM, BM x BN, BK=64, dbuf, async staging ----------------
// FUSE 0: fp32 out O0[row*768+col] (o-proj)
// FUSE 1: col0<768 -> bf16 O0 (lqkv); col0==768 -> rope -> qrb (O1); col0==832 -> rope -> krb (O2)
// FUSE 2: col<768 -> O0 qbuf [S][NH*64]; col<1536 -> O1 kbuf; else O2 vbT[h][d][SEQ]; A offset 384 when col0>=768
template <int FUSE, int BM, int BN>
__global__ __launch_bounds__(256)
void gemm_mfma_kernel(const unsigned short* __restrict__ A, const unsigned short* __restrict__ Bt,
                      const float* __restrict__ bias,
                      void* __restrict__ O0, void* __restrict__ O1, void* __restrict__ O2,
                      int K, int lda) {
    constexpr int MI = BM / 32;
    constexpr int NI = BN / 32;
    constexpr int AI = BM / 32;
    constexpr int BI = BN / 32;
    __shared__ unsigned short As[2][BM * 64];  // (row, c) holds global chunk (row, c^(row&7))
    __shared__ unsigned short Bs[2][BN * 64];
    const int tid = threadIdx.x;
    const int w = tid >> 6, lane = tid & 63, lr = lane & 15, lg = lane >> 4;
    const int row0 = blockIdx.y * BM, col0 = blockIdx.x * BN;
    const int wr = (w >> 1) * (BM / 2), wc = (w & 1) * (BN / 2);
    const unsigned short* Ab = A + ((FUSE == 2 && col0 >= 768) ? 384 : 0);

    f32x4 acc[MI][NI];
#pragma unroll
    for (int i = 0; i < MI; ++i)
#pragma unroll
        for (int j = 0; j < NI; ++j) acc[i][j] = f32x4{0.f, 0.f, 0.f, 0.f};

    auto stage = [&](int buf, int kt) {
#pragma unroll
        for (int i = 0; i < AI; ++i) {
            int c = tid + i * 256;
            int row = c >> 3, dgL = c & 7;
            gl_lds16(Ab + (size_t)(row0 + row) * lda + kt + (dgL ^ (row & 7)) * 8, &As[buf][c * 8]);
        }
#pragma unroll
        for (int i = 0; i < BI; ++i) {
            int c = tid + i * 256;
            int n = c >> 3, dgL = c & 7;
            gl_lds16(Bt + (size_t)(col0 + n) * K + kt + (dgL ^ (n & 7)) * 8, &Bs[buf][c * 8]);
        }
    };

    const int nkt = K >> 6;
    stage(0, 0);
    for (int t = 0; t < nkt; ++t) {
        __syncthreads();
        if (t + 1 < nkt) stage((t + 1) & 1, (t + 1) << 6);
        const unsigned short* asb = As[t & 1];
        const unsigned short* bsb = Bs[t & 1];
#pragma unroll
        for (int kk = 0; kk < 2; ++kk) {
            const int kbyte = kk * 64 + lg * 16;
#pragma unroll
            for (int mi = 0; mi < MI; ++mi) {
                const int row = wr + mi * 16 + lr;
                s16x8 a = *(const s16x8*)&asb[row * 64 + ((kbyte ^ ((row & 7) << 4)) >> 1)];
#pragma unroll
                for (int ni = 0; ni < NI; ++ni) {
                    const int n = wc + ni * 16 + lr;
                    s16x8 bfr = *(const s16x8*)&bsb[n * 64 + ((kbyte ^ ((n & 7) << 4)) >> 1)];
                    acc[mi][ni] = __builtin_amdgcn_mfma_f32_16x16x32_bf16(a, bfr, acc[mi][ni], 0, 0, 0);
                }
            }
        }
    }

    if constexpr (FUSE == 1) {
        if (col0 >= 768) {
            // ---- fused rope epilogue: this block holds the full BM x 64 qr/kr tile ----
            __syncthreads();
            float* rt = (float*)&As[0][0];
#pragma unroll
            for (int mi = 0; mi < MI; ++mi)
#pragma unroll
                for (int ni = 0; ni < NI; ++ni) {
                    const int cl = wc + ni * 16 + lr;
                    const float bv = bias[col0 + cl];
#pragma unroll
                    for (int j = 0; j < 4; ++j)
                        rt[(wr + mi * 16 + lg * 4 + j) * 64 + cl] = acc[mi][ni][j] + bv;
                }
            __syncthreads();
            unsigned short* dst = (col0 == 768) ? (unsigned short*)O1 : (unsigned short*)O2;
            constexpr int TPR = 256 / BM;
            constexpr int CNT = 32 / TPR;
            const int row = tid / TPR;
            const int i0 = (tid % TPR) * CNT;
            const float srow = (float)(row0 + row);
#pragma unroll
            for (int ii = 0; ii < CNT; ++ii) {
                const int i = i0 + ii;
                float a = rt[row * 64 + i], b = rt[row * 64 + 32 + i];
                float div = expf((float)(2 * i) * (-logf(10000.0f) / 64.0f));
                float emb = srow * div;
                float sn, cs;
                __sincosf(emb, &sn, &cs);
                dst[(size_t)(row0 + row) * 64 + i]      = f2bf(a * cs - b * sn);
                dst[(size_t)(row0 + row) * 64 + 32 + i] = f2bf(b * cs + a * sn);
            }
            return;
        }
    }

#pragma unroll
    for (int mi = 0; mi < MI; ++mi) {
#pragma unroll
        for (int ni = 0; ni < NI; ++ni) {
            const int col = col0 + wc + ni * 16 + lr;
            const float bv = bias[col];
            const int rbase = row0 + wr + mi * 16 + lg * 4;
            if (FUSE == 0) {
#pragma unroll
                for (int j = 0; j < 4; ++j)
                    ((float*)O0)[(size_t)(rbase + j) * HDIM + col] = acc[mi][ni][j] + bv;
            } else if (FUSE == 1) {
#pragma unroll
                for (int j = 0; j < 4; ++j)
                    ((unsigned short*)O0)[(size_t)(rbase + j) * HDIM + col] = f2bf(acc[mi][ni][j] + bv);
            } else {
                if (col < 768) {
                    const int hh = col >> 6, d = col & 63;
#pragma unroll
                    for (int j = 0; j < 4; ++j)
                        ((unsigned short*)O0)[(size_t)(rbase + j) * (NH * 64) + hh * 64 + d] = f2bf(acc[mi][ni][j] + bv);
                } else if (col < 1536) {
                    const int c2 = col - 768;
                    const int hh = c2 >> 6, d = c2 & 63;
#pragma unroll
                    for (int j = 0; j < 4; ++j)
                        ((unsigned short*)O1)[(size_t)(rbase + j) * (NH * 64) + hh * 64 + d] = f2bf(acc[mi][ni][j] + bv);
                } else {
                    const int c2 = col - 1536;
                    const int hh = c2 >> 7, d = c2 & 127;
                    u16x4 pk;
#pragma unroll
                    for (int j = 0; j < 4; ++j) pk[j] = f2bf(acc[mi][ni][j] + bv);
                    *(u16x4*)((unsigned short*)O2 + (size_t)(hh * 128 + d) * SEQ + rbase) = pk;
                }
            }
        }
    }
}

// ---------------- MFMA flash attention (single-buffered staging, 4 blocks/CU, setprio) ----------------
__global__ __launch_bounds__(256, 4)
void attn_mfma_kernel(const unsigned short* __restrict__ qbuf,
                      const unsigned short* __restrict__ qrb,
                      const unsigned short* __restrict__ kbuf,
                      const unsigned short* __restrict__ krb,
                      const unsigned short* __restrict__ vbT,
                      const int* __restrict__ lastEOT,
                      unsigned short* __restrict__ aob) {
    __shared__ unsigned short Ks[64 * 128];   // (key, c) holds global chunk (key, c^(key&7))
    __shared__ unsigned short Vt[128 * 64];   // (dim, c) holds global chunk (dim, c^(dim&7))
    __shared__ unsigned short Pa[4][16 * 64];

    const int h    = blockIdx.y;
    const int q0   = blockIdx.x * 64;
    const int tid  = threadIdx.x;
    const int w    = tid >> 6;
    const int lane = tid & 63;
    const int lr   = lane & 15;
    const int lg   = lane >> 4;

    const int qrow0 = q0 + w * 16 + lg * 4;
    const int qminw = q0 + w * 16;
    const int qmaxw = qminw + 15;
    const int leMinW = lastEOT[qminw];
    const int leMaxW = lastEOT[qmaxw];
    int rs[4];
#pragma unroll
    for (int r = 0; r < 4; ++r) rs[r] = lastEOT[qrow0 + r];

    s16x8 aq[4];
    {
        const int s = q0 + w * 16 + lr;
        const unsigned short* qp = qbuf + ((size_t)s * NH + h) * 64 + lg * 8;
        aq[0] = *(const s16x8*)qp;
        aq[1] = *(const s16x8*)(qp + 32);
        const unsigned short* qrp = qrb + (size_t)s * 64 + lg * 8;
        aq[2] = *(const s16x8*)qrp;
        aq[3] = *(const s16x8*)(qrp + 32);
    }

    const int kt0 = lastEOT[q0] & ~63;
    const int ntiles = (q0 + 64 - kt0) >> 6;

    float lsum[4] = {0.f, 0.f, 0.f, 0.f};
    f32x4 o[8];
#pragma unroll
    for (int n = 0; n < 8; ++n) o[n] = f32x4{0.f, 0.f, 0.f, 0.f};

    // exp(s*scale) = exp2(s * scale*log2(e))
    const float scl2 = 0.088388347648318447f * 1.4426950408889634f;

    auto stage = [&](int k0) {
        // interleave K and V issues: spreads the two address streams in the vmcnt queue
#pragma unroll
        for (int i = 0; i < 4; ++i) {
            {
                const int c = tid + i * 256;
                const int key = c >> 4, dgL = c & 15;
                const int dg = dgL ^ (key & 7);
                const unsigned short* src = (dg < 8)
                    ? kbuf + ((size_t)(k0 + key) * NH + h) * 64 + dg * 8
                    : krb + (size_t)(k0 + key) * 64 + (dg - 8) * 8;
                gl_lds16(src, &Ks[c * 8]);
            }
            {
                const int c = tid + i * 256;
                const int dim = c >> 3, kgL = c & 7;
                gl_lds16(vbT + ((size_t)h * 128 + dim) * SEQ + k0 + (kgL ^ (dim & 7)) * 8, &Vt[c * 8]);
            }
        }
    };

    stage(kt0);
    for (int t = 0; t < ntiles; ++t) {
        const int k0 = kt0 + t * 64;
        __syncthreads();                          // staged tile landed (drains vmcnt)

        const bool skip = (k0 > qmaxw || k0 + 63 < leMinW);  // wave-uniform
        if (!skip) {
            // ---- S = Q @ K^T ----
            f32x4 s[4];
#pragma unroll
            for (int n = 0; n < 4; ++n) s[n] = f32x4{0.f, 0.f, 0.f, 0.f};
            __builtin_amdgcn_s_setprio(1);
#pragma unroll
            for (int n = 0; n < 4; ++n) {
                const int key = n * 16 + lr;
                const int swz = (key & 7) << 4;
#pragma unroll
                for (int kk = 0; kk < 4; ++kk) {
                    const int colb = (kk * 64 + lg * 16) ^ swz;
                    s16x8 bk = *(const s16x8*)&Ks[key * 128 + (colb >> 1)];
                    s[n] = __builtin_amdgcn_mfma_f32_16x16x32_bf16(aq[kk], bk, s[n], 0, 0, 0);
                }
            }
            __builtin_amdgcn_s_setprio(0);

            // ---- p = exp2(s*scl2), masked on boundary tiles ----
            const bool full = (k0 + 63 <= qminw) && (k0 >= leMaxW);
            float p[4][4];
            if (full) {
#pragma unroll
                for (int n = 0; n < 4; ++n)
#pragma unroll
                    for (int r = 0; r < 4; ++r) {
                        float pv = exp2f(s[n][r] * scl2);
                        p[n][r] = pv;
                        lsum[r] += pv;
                    }
            } else {
#pragma unroll
                for (int n = 0; n < 4; ++n) {
                    const int k = k0 + n * 16 + lr;
#pragma unroll
                    for (int r = 0; r < 4; ++r) {
                        const int qq = qrow0 + r;
                        const bool valid = (k <= qq) && (k >= rs[r]);
                        float pv = valid ? exp2f(s[n][r] * scl2) : 0.f;
                        p[n][r] = pv;
                        lsum[r] += pv;
                    }
                }
            }

            // ---- P -> per-wave LDS (transpose to A-fragment layout) ----
#pragma unroll
            for (int n = 0; n < 4; ++n)
#pragma unroll
                for (int r = 0; r < 4; ++r) {
                    const int ql = lg * 4 + r;
                    const int key = n * 16 + lr;
                    const int byteoff = (key * 2) ^ ((ql & 7) << 4);
                    Pa[w][ql * 64 + (byteoff >> 1)] = f2bf(p[n][r]);
                }

            // ---- O += P @ V ----
            __builtin_amdgcn_s_setprio(1);
#pragma unroll
            for (int kk2 = 0; kk2 < 2; ++kk2) {
                const int keyb = kk2 * 32 + lg * 8;
                s16x8 ap = *(const s16x8*)&Pa[w][lr * 64 + ((((keyb * 2) ^ ((lr & 7) << 4))) >> 1)];
#pragma unroll
                for (int n = 0; n < 8; ++n) {
                    const int dim = n * 16 + lr;
                    s16x8 bv = *(const s16x8*)&Vt[dim * 64 + ((((keyb * 2) ^ ((dim & 7) << 4))) >> 1)];
                    o[n] = __builtin_amdgcn_mfma_f32_16x16x32_bf16(ap, bv, o[n], 0, 0, 0);
                }
            }
            __builtin_amdgcn_s_setprio(0);
        }

        __syncthreads();                          // all waves done with Ks/Vt
        if (t + 1 < ntiles) stage(k0 + 64);       // overwrite buffer for next tile
    }

#pragma unroll
    for (int off = 1; off < 16; off <<= 1)
#pragma unroll
        for (int r = 0; r < 4; ++r) lsum[r] += __shfl_xor(lsum[r], off);

    float inv[4];
#pragma unroll
    for (int r = 0; r < 4; ++r) inv[r] = 1.f / lsum[r];
#pragma unroll
    for (int n = 0; n < 8; ++n)
#pragma unroll
        for (int r = 0; r < 4; ++r) {
            const int qq = qrow0 + r;
            aob[(size_t)qq * (2 * HDIM) + h * 128 + n * 16 + lr] = f2bf(o[n][r] * inv[r]);
        }
}

extern "C" void kernel_launch(void* const* d_in, const int* in_sizes, int n_in,
                              void* d_out, int out_size, void* d_ws, size_t ws_size,
                              hipStream_t stream) {
    (void)in_sizes; (void)n_in; (void)out_size; (void)ws_size;
    const float* x     = (const float*)d_in[0];
    const int*   tok   = (const int*)d_in[1];
    const float* qd_w  = (const float*)d_in[2];
    const float* qd_b  = (const float*)d_in[3];
    const float* qu_w  = (const float*)d_in[4];
    const float* qu_b  = (const float*)d_in[5];
    const float* qr_w  = (const float*)d_in[6];
    const float* qr_b  = (const float*)d_in[7];
    const float* kvd_w = (const float*)d_in[8];
    const float* kvd_b = (const float*)d_in[9];
    const float* ku_w  = (const float*)d_in[10];
    const float* ku_b  = (const float*)d_in[11];
    const float* vu_w  = (const float*)d_in[12];
    const float* vu_b  = (const float*)d_in[13];
    const float* kr_w  = (const float*)d_in[14];
    const float* kr_b  = (const float*)d_in[15];
    const float* o_w   = (const float*)d_in[16];
    const float* o_b   = (const float*)d_in[17];
    float* out = (float*)d_out;

    unsigned short* ws = (unsigned short*)d_ws;
    unsigned short* xb   = ws;                              // 2048*768
    unsigned short* lqkv = xb   + (size_t)SEQ * HDIM;       // 2048*768
    unsigned short* qbuf = lqkv + (size_t)SEQ * HDIM;       // 2048*768 ([S][NH*64])
    unsigned short* kbuf = qbuf + (size_t)SEQ * NH * 64;    // 2048*768
    unsigned short* qrb  = kbuf + (size_t)SEQ * NH * 64;    // 2048*64
    unsigned short* krb  = qrb  + (size_t)SEQ * 64;         // 2048*64
    unsigned short* vbT  = krb  + (size_t)SEQ * 64;         // 12*128*2048
    unsigned short* aob  = vbT  + (size_t)NH * 128 * SEQ;   // 2048*1536
    unsigned short* B1   = aob  + (size_t)SEQ * 2 * HDIM;   // [qd|kvd|qr|kr]^T : 896 x 768
    unsigned short* B2   = B1   + (size_t)896 * HDIM;       // [qu|ku|vu]^T     : 3072 x 384
    unsigned short* to   = B2   + (size_t)3072 * LR;        // o^T              : 768 x 1536
    float* biasA = (float*)(to + (size_t)HDIM * 2 * HDIM);  // 896
    float* biasB = biasA + 896;                             // 3072
    int* lastEOT = (int*)(biasB + 3072);

    unsigned short* tqd  = B1;
    unsigned short* tkvd = B1 + (size_t)384 * 768;
    unsigned short* tqr  = B1 + (size_t)768 * 768;
    unsigned short* tkr  = B1 + (size_t)832 * 768;
    unsigned short* tqu  = B2;
    unsigned short* tku  = B2 + (size_t)768 * 384;
    unsigned short* tvu  = B2 + (size_t)1536 * 384;

    transpose_pack_all<<<1130, 256, 0, stream>>>(qd_w, qu_w, qr_w, kvd_w, ku_w, vu_w, kr_w, o_w,
                                                 tqd, tqu, tqr, tkvd, tku, tvu, tkr, to,
                                                 x, xb, qd_b, kvd_b, qr_b, kr_b, qu_b, ku_b, vu_b,
                                                 biasA, biasB, tok, lastEOT);

    // fused down + rotary projections: BM=64 -> 448 blocks
    gemm_mfma_kernel<1, 64, 64><<<dim3(14, 32), 256, 0, stream>>>(xb, B1, biasA, lqkv, qrb, krb, HDIM, HDIM);
    // fused up projections: 128x64 (48 KB LDS -> 3 blocks/CU, 768 blocks)
    gemm_mfma_kernel<2, 128, 64><<<dim3(48, 16), 256, 0, stream>>>(lqkv, B2, biasB, qbuf, kbuf, vbT, LR, HDIM);

    attn_mfma_kernel<<<dim3(SEQ / 64, NH), 256, 0, stream>>>(qbuf, qrb, kbuf, krb, vbT, lastEOT, aob);

    // output projection: BM=64 -> 384 blocks
    gemm_mfma_kernel<0, 64, 64><<<dim3(12, 32), 256, 0, stream>>>(aob, to, o_b, out, nullptr, nullptr, 2 * HDIM, 2 * HDIM);
}

// Round 13
// 74.185 us; speedup vs baseline: 1.4319x; 1.4319x over previous
//
#include <hip/hip_runtime.h>
#include <hip/hip_bf16.h>
#include <math.h>

#define SEQ 2048
#define HDIM 768
#define NH 12
#define HD 64
#define LR 384
#define EOT 50256

typedef short s16x8 __attribute__((ext_vector_type(8)));
typedef float f32x4 __attribute__((ext_vector_type(4)));
typedef unsigned short u16x8 __attribute__((ext_vector_type(8)));
typedef unsigned short u16x4 __attribute__((ext_vector_type(4)));

__device__ __forceinline__ unsigned short f2bf(float f) {
    union { float f; unsigned u; } v; v.f = f;
    unsigned r = v.u + 0x7fffu + ((v.u >> 16) & 1u);
    return (unsigned short)(r >> 16);
}

// async 16B global->LDS (linear dest; caller pre-swizzles the SOURCE chunk)
__device__ __forceinline__ void gl_lds16(const void* g, void* l) {
    __builtin_amdgcn_global_load_lds(
        (const __attribute__((address_space(1))) unsigned int*)g,
        (__attribute__((address_space(3))) unsigned int*)l, 16, 0, 0);
}

// ---------------- weight transpose+pack + x pack + bias concat + EOT scan ----------------
__global__ __launch_bounds__(256)
void transpose_pack_all(const float* w0, const float* w1, const float* w2, const float* w3,
                        const float* w4, const float* w5, const float* w6, const float* w7,
                        unsigned short* t0, unsigned short* t1, unsigned short* t2, unsigned short* t3,
                        unsigned short* t4, unsigned short* t5, unsigned short* t6, unsigned short* t7,
                        const float* x, unsigned short* xb,
                        const float* qd_b, const float* kvd_b, const float* qr_b, const float* kr_b,
                        const float* qu_b, const float* ku_b, const float* vu_b,
                        float* biasA, float* biasB,
                        const int* tok, int* lastEOT) {
    __shared__ float t[64][65];
    __shared__ int smax[256];
    int b = blockIdx.x;
    const int tid = threadIdx.x;
    if (b == 1129) {  // parallel lastEOT scan
        const int base = tid * 8;
        int v[8];
        int mx = 0;
#pragma unroll
        for (int j = 0; j < 8; ++j) {
            int i = base + j;
            int f = (tok[i] == EOT) ? i : 0;
            mx = max(mx, f);
            v[j] = mx;
        }
        smax[tid] = mx;
        __syncthreads();
        for (int off = 1; off < 256; off <<= 1) {
            int val = (tid >= off) ? smax[tid - off] : 0;
            __syncthreads();
            smax[tid] = max(smax[tid], val);
            __syncthreads();
        }
        int pre = (tid > 0) ? smax[tid - 1] : 0;
#pragma unroll
        for (int j = 0; j < 8; ++j) lastEOT[base + j] = max(pre, v[j]);
        return;
    }
    if (b == 1128) {  // bias concat
        for (int i = tid; i < 896; i += 256) {
            float v;
            if (i < 384) v = qd_b[i];
            else if (i < 768) v = kvd_b[i - 384];
            else if (i < 832) v = qr_b[i - 768];
            else v = kr_b[i - 832];
            biasA[i] = v;
        }
        for (int i = tid; i < 3072; i += 256) {
            float v;
            if (i < 768) v = qu_b[i];
            else if (i < 1536) v = ku_b[i - 768];
            else v = vu_b[i - 1536];
            biasB[i] = v;
        }
        return;
    }
    if (b >= 744) {  // x pack: 384 tiles of 64x64 (float4 in, u16x4 out)
        int b2 = b - 744;
        int row0 = (b2 / 12) * 64, col0 = (b2 % 12) * 64;
#pragma unroll
        for (int i = 0; i < 4; ++i) {
            int idx = tid + i * 256;
            int r = idx >> 4, c4 = (idx & 15) * 4;
            float4 v = *(const float4*)(x + (size_t)(row0 + r) * HDIM + col0 + c4);
            u16x4 pk = {f2bf(v.x), f2bf(v.y), f2bf(v.z), f2bf(v.w)};
            *(u16x4*)(xb + (size_t)(row0 + r) * HDIM + col0 + c4) = pk;
        }
        return;
    }
    const float* W; unsigned short* T; int K, N, lt;
    if      (b < 72)  { W = w0; T = t0; K = 768;  N = 384;  lt = b; }
    else if (b < 144) { W = w1; T = t1; K = 384;  N = 768;  lt = b - 72; }
    else if (b < 156) { W = w2; T = t2; K = 768;  N = 64;   lt = b - 144; }
    else if (b < 228) { W = w3; T = t3; K = 768;  N = 384;  lt = b - 156; }
    else if (b < 300) { W = w4; T = t4; K = 384;  N = 768;  lt = b - 228; }
    else if (b < 444) { W = w5; T = t5; K = 384;  N = 1536; lt = b - 300; }
    else if (b < 456) { W = w6; T = t6; K = 768;  N = 64;   lt = b - 444; }
    else              { W = w7; T = t7; K = 1536; N = 768;  lt = b - 456; }
    const int tn = N >> 6;
    const int n0 = (lt % tn) * 64, k0 = (lt / tn) * 64;
#pragma unroll
    for (int i = 0; i < 4; ++i) {
        int idx = tid + i * 256;
        int k = idx >> 4, c4 = (idx & 15) * 4;
        float4 v = *(const float4*)(W + (size_t)(k0 + k) * N + n0 + c4);
        t[k][c4] = v.x; t[k][c4 + 1] = v.y; t[k][c4 + 2] = v.z; t[k][c4 + 3] = v.w;
    }
    __syncthreads();
#pragma unroll
    for (int i = 0; i < 4; ++i) {
        int idx = tid + i * 256;
        int n = idx >> 4, k4 = (idx & 15) * 4;
        u16x4 pk = {f2bf(t[k4][n]), f2bf(t[k4 + 1][n]), f2bf(t[k4 + 2][n]), f2bf(t[k4 + 3][n])};
        *(u16x4*)(T + (size_t)(n0 + n) * K + k0 + k4) = pk;
    }
}

// ---------------- bf16 MFMA GEMM, BM x BN, BK=64, dbuf, async staging ----------------
// FUSE 0: fp32 out O0[row*768+col] (o-proj)
// FUSE 1: col0<768 -> bf16 O0 (lqkv); col0==768 -> rope -> qrb (O1); col0==832 -> rope -> krb (O2)
// FUSE 2: col<768 -> O0 qbuf [S][NH*64]; col<1536 -> O1 kbuf; else O2 vbT[h][d][SEQ]; A offset 384 when col0>=768
template <int FUSE, int BM, int BN>
__global__ __launch_bounds__(256)
void gemm_mfma_kernel(const unsigned short* __restrict__ A, const unsigned short* __restrict__ Bt,
                      const float* __restrict__ bias,
                      void* __restrict__ O0, void* __restrict__ O1, void* __restrict__ O2,
                      int K, int lda) {
    constexpr int MI = BM / 32;
    constexpr int NI = BN / 32;
    constexpr int AI = BM / 32;
    constexpr int BI = BN / 32;
    __shared__ unsigned short As[2][BM * 64];  // (row, c) holds global chunk (row, c^(row&7))
    __shared__ unsigned short Bs[2][BN * 64];
    const int tid = threadIdx.x;
    const int w = tid >> 6, lane = tid & 63, lr = lane & 15, lg = lane >> 4;
    const int row0 = blockIdx.y * BM, col0 = blockIdx.x * BN;
    const int wr = (w >> 1) * (BM / 2), wc = (w & 1) * (BN / 2);
    const unsigned short* Ab = A + ((FUSE == 2 && col0 >= 768) ? 384 : 0);

    f32x4 acc[MI][NI];
#pragma unroll
    for (int i = 0; i < MI; ++i)
#pragma unroll
        for (int j = 0; j < NI; ++j) acc[i][j] = f32x4{0.f, 0.f, 0.f, 0.f};

    auto stage = [&](int buf, int kt) {
#pragma unroll
        for (int i = 0; i < AI; ++i) {
            int c = tid + i * 256;
            int row = c >> 3, dgL = c & 7;
            gl_lds16(Ab + (size_t)(row0 + row) * lda + kt + (dgL ^ (row & 7)) * 8, &As[buf][c * 8]);
        }
#pragma unroll
        for (int i = 0; i < BI; ++i) {
            int c = tid + i * 256;
            int n = c >> 3, dgL = c & 7;
            gl_lds16(Bt + (size_t)(col0 + n) * K + kt + (dgL ^ (n & 7)) * 8, &Bs[buf][c * 8]);
        }
    };

    const int nkt = K >> 6;
    stage(0, 0);
    for (int t = 0; t < nkt; ++t) {
        __syncthreads();
        if (t + 1 < nkt) stage((t + 1) & 1, (t + 1) << 6);
        const unsigned short* asb = As[t & 1];
        const unsigned short* bsb = Bs[t & 1];
#pragma unroll
        for (int kk = 0; kk < 2; ++kk) {
            const int kbyte = kk * 64 + lg * 16;
#pragma unroll
            for (int mi = 0; mi < MI; ++mi) {
                const int row = wr + mi * 16 + lr;
                s16x8 a = *(const s16x8*)&asb[row * 64 + ((kbyte ^ ((row & 7) << 4)) >> 1)];
#pragma unroll
                for (int ni = 0; ni < NI; ++ni) {
                    const int n = wc + ni * 16 + lr;
                    s16x8 bfr = *(const s16x8*)&bsb[n * 64 + ((kbyte ^ ((n & 7) << 4)) >> 1)];
                    acc[mi][ni] = __builtin_amdgcn_mfma_f32_16x16x32_bf16(a, bfr, acc[mi][ni], 0, 0, 0);
                }
            }
        }
    }

    if constexpr (FUSE == 1) {
        if (col0 >= 768) {
            // ---- fused rope epilogue: this block holds the full BM x 64 qr/kr tile ----
            __syncthreads();
            float* rt = (float*)&As[0][0];
#pragma unroll
            for (int mi = 0; mi < MI; ++mi)
#pragma unroll
                for (int ni = 0; ni < NI; ++ni) {
                    const int cl = wc + ni * 16 + lr;
                    const float bv = bias[col0 + cl];
#pragma unroll
                    for (int j = 0; j < 4; ++j)
                        rt[(wr + mi * 16 + lg * 4 + j) * 64 + cl] = acc[mi][ni][j] + bv;
                }
            __syncthreads();
            unsigned short* dst = (col0 == 768) ? (unsigned short*)O1 : (unsigned short*)O2;
            constexpr int TPR = 256 / BM;
            constexpr int CNT = 32 / TPR;
            const int row = tid / TPR;
            const int i0 = (tid % TPR) * CNT;
            const float srow = (float)(row0 + row);
#pragma unroll
            for (int ii = 0; ii < CNT; ++ii) {
                const int i = i0 + ii;
                float a = rt[row * 64 + i], b = rt[row * 64 + 32 + i];
                float div = expf((float)(2 * i) * (-logf(10000.0f) / 64.0f));
                float emb = srow * div;
                float sn, cs;
                __sincosf(emb, &sn, &cs);
                dst[(size_t)(row0 + row) * 64 + i]      = f2bf(a * cs - b * sn);
                dst[(size_t)(row0 + row) * 64 + 32 + i] = f2bf(b * cs + a * sn);
            }
            return;
        }
    }

#pragma unroll
    for (int mi = 0; mi < MI; ++mi) {
#pragma unroll
        for (int ni = 0; ni < NI; ++ni) {
            const int col = col0 + wc + ni * 16 + lr;
            const float bv = bias[col];
            const int rbase = row0 + wr + mi * 16 + lg * 4;
            if (FUSE == 0) {
#pragma unroll
                for (int j = 0; j < 4; ++j)
                    ((float*)O0)[(size_t)(rbase + j) * HDIM + col] = acc[mi][ni][j] + bv;
            } else if (FUSE == 1) {
#pragma unroll
                for (int j = 0; j < 4; ++j)
                    ((unsigned short*)O0)[(size_t)(rbase + j) * HDIM + col] = f2bf(acc[mi][ni][j] + bv);
            } else {
                if (col < 768) {
                    const int hh = col >> 6, d = col & 63;
#pragma unroll
                    for (int j = 0; j < 4; ++j)
                        ((unsigned short*)O0)[(size_t)(rbase + j) * (NH * 64) + hh * 64 + d] = f2bf(acc[mi][ni][j] + bv);
                } else if (col < 1536) {
                    const int c2 = col - 768;
                    const int hh = c2 >> 6, d = c2 & 63;
#pragma unroll
                    for (int j = 0; j < 4; ++j)
                        ((unsigned short*)O1)[(size_t)(rbase + j) * (NH * 64) + hh * 64 + d] = f2bf(acc[mi][ni][j] + bv);
                } else {
                    const int c2 = col - 1536;
                    const int hh = c2 >> 7, d = c2 & 127;
                    u16x4 pk;
#pragma unroll
                    for (int j = 0; j < 4; ++j) pk[j] = f2bf(acc[mi][ni][j] + bv);
                    *(u16x4*)((unsigned short*)O2 + (size_t)(hh * 128 + d) * SEQ + rbase) = pk;
                }
            }
        }
    }
}

// ---------------- MFMA flash attention (single-buffered staging, 4 blocks/CU) ----------------
// LDS = 16+16+8 = 40 KB -> 4 blocks/CU (exactly 160 KiB), 16 waves/CU.
// NOTE: no __launch_bounds__ min-waves arg — R12 showed (256,4) forces VGPR 72->64
// and spills (WRITE_SIZE 3x, attn 13us -> 59us). Natural 72 VGPR still fits 4 blocks/CU.
__global__ __launch_bounds__(256)
void attn_mfma_kernel(const unsigned short* __restrict__ qbuf,
                      const unsigned short* __restrict__ qrb,
                      const unsigned short* __restrict__ kbuf,
                      const unsigned short* __restrict__ krb,
                      const unsigned short* __restrict__ vbT,
                      const int* __restrict__ lastEOT,
                      unsigned short* __restrict__ aob) {
    __shared__ unsigned short Ks[64 * 128];   // (key, c) holds global chunk (key, c^(key&7))
    __shared__ unsigned short Vt[128 * 64];   // (dim, c) holds global chunk (dim, c^(dim&7))
    __shared__ unsigned short Pa[4][16 * 64];

    const int h    = blockIdx.y;
    const int q0   = blockIdx.x * 64;
    const int tid  = threadIdx.x;
    const int w    = tid >> 6;
    const int lane = tid & 63;
    const int lr   = lane & 15;
    const int lg   = lane >> 4;

    const int qrow0 = q0 + w * 16 + lg * 4;
    const int qminw = q0 + w * 16;
    const int qmaxw = qminw + 15;
    const int leMinW = lastEOT[qminw];
    const int leMaxW = lastEOT[qmaxw];
    int rs[4];
#pragma unroll
    for (int r = 0; r < 4; ++r) rs[r] = lastEOT[qrow0 + r];

    s16x8 aq[4];
    {
        const int s = q0 + w * 16 + lr;
        const unsigned short* qp = qbuf + ((size_t)s * NH + h) * 64 + lg * 8;
        aq[0] = *(const s16x8*)qp;
        aq[1] = *(const s16x8*)(qp + 32);
        const unsigned short* qrp = qrb + (size_t)s * 64 + lg * 8;
        aq[2] = *(const s16x8*)qrp;
        aq[3] = *(const s16x8*)(qrp + 32);
    }

    const int kt0 = lastEOT[q0] & ~63;
    const int ntiles = (q0 + 64 - kt0) >> 6;

    float lsum[4] = {0.f, 0.f, 0.f, 0.f};
    f32x4 o[8];
#pragma unroll
    for (int n = 0; n < 8; ++n) o[n] = f32x4{0.f, 0.f, 0.f, 0.f};

    // exp(s*scale) = exp2(s * scale*log2(e))
    const float scl2 = 0.088388347648318447f * 1.4426950408889634f;

    auto stage = [&](int k0) {
#pragma unroll
        for (int i = 0; i < 4; ++i) {
            const int c = tid + i * 256;
            const int key = c >> 4, dgL = c & 15;
            const int dg = dgL ^ (key & 7);
            const unsigned short* src = (dg < 8)
                ? kbuf + ((size_t)(k0 + key) * NH + h) * 64 + dg * 8
                : krb + (size_t)(k0 + key) * 64 + (dg - 8) * 8;
            gl_lds16(src, &Ks[c * 8]);
        }
#pragma unroll
        for (int i = 0; i < 4; ++i) {
            const int c = tid + i * 256;
            const int dim = c >> 3, kgL = c & 7;
            gl_lds16(vbT + ((size_t)h * 128 + dim) * SEQ + k0 + (kgL ^ (dim & 7)) * 8, &Vt[c * 8]);
        }
    };

    stage(kt0);
    for (int t = 0; t < ntiles; ++t) {
        const int k0 = kt0 + t * 64;
        __syncthreads();                          // staged tile landed (drains vmcnt)

        const bool skip = (k0 > qmaxw || k0 + 63 < leMinW);  // wave-uniform
        if (!skip) {
            // ---- S = Q @ K^T ----
            f32x4 s[4];
#pragma unroll
            for (int n = 0; n < 4; ++n) s[n] = f32x4{0.f, 0.f, 0.f, 0.f};
#pragma unroll
            for (int n = 0; n < 4; ++n) {
                const int key = n * 16 + lr;
                const int swz = (key & 7) << 4;
#pragma unroll
                for (int kk = 0; kk < 4; ++kk) {
                    const int colb = (kk * 64 + lg * 16) ^ swz;
                    s16x8 bk = *(const s16x8*)&Ks[key * 128 + (colb >> 1)];
                    s[n] = __builtin_amdgcn_mfma_f32_16x16x32_bf16(aq[kk], bk, s[n], 0, 0, 0);
                }
            }

            // ---- p = exp2(s*scl2), masked on boundary tiles ----
            const bool full = (k0 + 63 <= qminw) && (k0 >= leMaxW);
            float p[4][4];
            if (full) {
#pragma unroll
                for (int n = 0; n < 4; ++n)
#pragma unroll
                    for (int r = 0; r < 4; ++r) {
                        float pv = exp2f(s[n][r] * scl2);
                        p[n][r] = pv;
                        lsum[r] += pv;
                    }
            } else {
#pragma unroll
                for (int n = 0; n < 4; ++n) {
                    const int k = k0 + n * 16 + lr;
#pragma unroll
                    for (int r = 0; r < 4; ++r) {
                        const int qq = qrow0 + r;
                        const bool valid = (k <= qq) && (k >= rs[r]);
                        float pv = valid ? exp2f(s[n][r] * scl2) : 0.f;
                        p[n][r] = pv;
                        lsum[r] += pv;
                    }
                }
            }

            // ---- P -> per-wave LDS (transpose to A-fragment layout) ----
#pragma unroll
            for (int n = 0; n < 4; ++n)
#pragma unroll
                for (int r = 0; r < 4; ++r) {
                    const int ql = lg * 4 + r;
                    const int key = n * 16 + lr;
                    const int byteoff = (key * 2) ^ ((ql & 7) << 4);
                    Pa[w][ql * 64 + (byteoff >> 1)] = f2bf(p[n][r]);
                }

            // ---- O += P @ V ----
#pragma unroll
            for (int kk2 = 0; kk2 < 2; ++kk2) {
                const int keyb = kk2 * 32 + lg * 8;
                s16x8 ap = *(const s16x8*)&Pa[w][lr * 64 + ((((keyb * 2) ^ ((lr & 7) << 4))) >> 1)];
#pragma unroll
                for (int n = 0; n < 8; ++n) {
                    const int dim = n * 16 + lr;
                    s16x8 bv = *(const s16x8*)&Vt[dim * 64 + ((((keyb * 2) ^ ((dim & 7) << 4))) >> 1)];
                    o[n] = __builtin_amdgcn_mfma_f32_16x16x32_bf16(ap, bv, o[n], 0, 0, 0);
                }
            }
        }

        __syncthreads();                          // all waves done with Ks/Vt
        if (t + 1 < ntiles) stage(k0 + 64);       // overwrite buffer for next tile
    }

#pragma unroll
    for (int off = 1; off < 16; off <<= 1)
#pragma unroll
        for (int r = 0; r < 4; ++r) lsum[r] += __shfl_xor(lsum[r], off);

    float inv[4];
#pragma unroll
    for (int r = 0; r < 4; ++r) inv[r] = 1.f / lsum[r];
#pragma unroll
    for (int n = 0; n < 8; ++n)
#pragma unroll
        for (int r = 0; r < 4; ++r) {
            const int qq = qrow0 + r;
            aob[(size_t)qq * (2 * HDIM) + h * 128 + n * 16 + lr] = f2bf(o[n][r] * inv[r]);
        }
}

extern "C" void kernel_launch(void* const* d_in, const int* in_sizes, int n_in,
                              void* d_out, int out_size, void* d_ws, size_t ws_size,
                              hipStream_t stream) {
    (void)in_sizes; (void)n_in; (void)out_size; (void)ws_size;
    const float* x     = (const float*)d_in[0];
    const int*   tok   = (const int*)d_in[1];
    const float* qd_w  = (const float*)d_in[2];
    const float* qd_b  = (const float*)d_in[3];
    const float* qu_w  = (const float*)d_in[4];
    const float* qu_b  = (const float*)d_in[5];
    const float* qr_w  = (const float*)d_in[6];
    const float* qr_b  = (const float*)d_in[7];
    const float* kvd_w = (const float*)d_in[8];
    const float* kvd_b = (const float*)d_in[9];
    const float* ku_w  = (const float*)d_in[10];
    const float* ku_b  = (const float*)d_in[11];
    const float* vu_w  = (const float*)d_in[12];
    const float* vu_b  = (const float*)d_in[13];
    const float* kr_w  = (const float*)d_in[14];
    const float* kr_b  = (const float*)d_in[15];
    const float* o_w   = (const float*)d_in[16];
    const float* o_b   = (const float*)d_in[17];
    float* out = (float*)d_out;

    unsigned short* ws = (unsigned short*)d_ws;
    unsigned short* xb   = ws;                              // 2048*768
    unsigned short* lqkv = xb   + (size_t)SEQ * HDIM;       // 2048*768
    unsigned short* qbuf = lqkv + (size_t)SEQ * HDIM;       // 2048*768 ([S][NH*64])
    unsigned short* kbuf = qbuf + (size_t)SEQ * NH * 64;    // 2048*768
    unsigned short* qrb  = kbuf + (size_t)SEQ * NH * 64;    // 2048*64
    unsigned short* krb  = qrb  + (size_t)SEQ * 64;         // 2048*64
    unsigned short* vbT  = krb  + (size_t)SEQ * 64;         // 12*128*2048
    unsigned short* aob  = vbT  + (size_t)NH * 128 * SEQ;   // 2048*1536
    unsigned short* B1   = aob  + (size_t)SEQ * 2 * HDIM;   // [qd|kvd|qr|kr]^T : 896 x 768
    unsigned short* B2   = B1   + (size_t)896 * HDIM;       // [qu|ku|vu]^T     : 3072 x 384
    unsigned short* to   = B2   + (size_t)3072 * LR;        // o^T              : 768 x 1536
    float* biasA = (float*)(to + (size_t)HDIM * 2 * HDIM);  // 896
    float* biasB = biasA + 896;                             // 3072
    int* lastEOT = (int*)(biasB + 3072);

    unsigned short* tqd  = B1;
    unsigned short* tkvd = B1 + (size_t)384 * 768;
    unsigned short* tqr  = B1 + (size_t)768 * 768;
    unsigned short* tkr  = B1 + (size_t)832 * 768;
    unsigned short* tqu  = B2;
    unsigned short* tku  = B2 + (size_t)768 * 384;
    unsigned short* tvu  = B2 + (size_t)1536 * 384;

    transpose_pack_all<<<1130, 256, 0, stream>>>(qd_w, qu_w, qr_w, kvd_w, ku_w, vu_w, kr_w, o_w,
                                                 tqd, tqu, tqr, tkvd, tku, tvu, tkr, to,
                                                 x, xb, qd_b, kvd_b, qr_b, kr_b, qu_b, ku_b, vu_b,
                                                 biasA, biasB, tok, lastEOT);

    // fused down + rotary projections: BM=64 -> 448 blocks
    gemm_mfma_kernel<1, 64, 64><<<dim3(14, 32), 256, 0, stream>>>(xb, B1, biasA, lqkv, qrb, krb, HDIM, HDIM);
    // fused up projections: 128x64 (48 KB LDS -> 3 blocks/CU, 768 blocks)
    gemm_mfma_kernel<2, 128, 64><<<dim3(48, 16), 256, 0, stream>>>(lqkv, B2, biasB, qbuf, kbuf, vbT, LR, HDIM);

    attn_mfma_kernel<<<dim3(SEQ / 64, NH), 256, 0, stream>>>(qbuf, qrb, kbuf, krb, vbT, lastEOT, aob);

    // output projection: BM=64 -> 384 blocks
    gemm_mfma_kernel<0, 64, 64><<<dim3(12, 32), 256, 0, stream>>>(aob, to, o_b, out, nullptr, nullptr, 2 * HDIM, 2 * HDIM);
}